// Round 1
// baseline (176.976 us; speedup 1.0000x reference)
//
#include <hip/hip_runtime.h>
#include <math.h>

// Problem constants (from setup_inputs): B=64, D=512, H=W=32 -> N=1024, NH=8, DH=64
#define BATCH 64
#define DCH   512
#define NPOS  1024
#define NH    8
#define DH    64
// scale = DH^-0.5 = 0.125 (folded into wq and bias)

// ---------------------------------------------------------------------------
// K1: wqT[c*8+h] = 0.125 * sum_d q[h,d] * Wkv[c, h*64+d]
// ---------------------------------------------------------------------------
__global__ __launch_bounds__(256) void k_wq(const float* __restrict__ q,
                                            const float* __restrict__ Wkv,
                                            float* __restrict__ wqT) {
    int c = blockIdx.x * 256 + threadIdx.x;  // 0..511
    if (c >= DCH) return;
    const float* wrow = Wkv + (size_t)c * (2 * DCH);
    #pragma unroll
    for (int h = 0; h < NH; ++h) {
        float s = 0.f;
        #pragma unroll 8
        for (int d = 0; d < DH; ++d)
            s = fmaf(q[h * DH + d], wrow[h * DH + d], s);
        wqT[c * NH + h] = 0.125f * s;
    }
}

// ---------------------------------------------------------------------------
// K2: bias[h*1024+n] = 0.125 * ( sum_i q[h,2i]*sin(n*dt_i)+q[h,2i+1]*cos(n*dt_i)
//                               + sum_d q[h,d]*bkv[h*64+d] )
// double precision trig (matches np float64 reference closely; kernel is tiny)
// ---------------------------------------------------------------------------
__global__ __launch_bounds__(256) void k_bias(const float* __restrict__ q,
                                              const float* __restrict__ bkv,
                                              float* __restrict__ bias) {
    int n = blockIdx.x * 256 + threadIdx.x;  // 0..1023
    if (n >= NPOS) return;
    double pq[NH];
    #pragma unroll
    for (int h = 0; h < NH; ++h) pq[h] = 0.0;
    const double kfac = -(log(10000.0) / (double)DH);  // * (2i)
    for (int i = 0; i < DH / 2; ++i) {
        double dt = exp((double)(2 * i) * kfac);
        double ang = (double)n * dt;
        double s = sin(ang), cth = cos(ang);
        #pragma unroll
        for (int h = 0; h < NH; ++h)
            pq[h] += (double)q[h * DH + 2 * i] * s + (double)q[h * DH + 2 * i + 1] * cth;
    }
    #pragma unroll
    for (int h = 0; h < NH; ++h) {
        double bq = 0.0;
        for (int d = 0; d < DH; ++d)
            bq += (double)q[h * DH + d] * (double)bkv[h * DH + d];
        bias[h * NPOS + n] = (float)(0.125 * (pq[h] + bq));
    }
}

// ---------------------------------------------------------------------------
// K3: partial dots.  grid (8, B): blockIdx.x = nt*2+cs (nt: n-tile of 256,
// cs: c-half of 256).  dots[(cs*B + b)*8*1024 + h*1024 + n]
// wqT reads are wave-uniform -> scalar loads; FMA with SGPR operand.
// ---------------------------------------------------------------------------
__global__ __launch_bounds__(256) void k_dots(const float* __restrict__ x,
                                              const float* __restrict__ wqT,
                                              const float* __restrict__ bias,
                                              float* __restrict__ dots) {
    int b  = blockIdx.y;
    int nt = blockIdx.x >> 1;
    int cs = blockIdx.x & 1;
    int n  = nt * 256 + threadIdx.x;
    int c0 = cs * 256;

    float acc[NH];
    #pragma unroll
    for (int h = 0; h < NH; ++h)
        acc[h] = (cs == 0) ? bias[h * NPOS + n] : 0.f;

    const float* xp = x + ((size_t)b * DCH + c0) * NPOS + n;
    const float* wp = wqT + c0 * NH;

    for (int c = 0; c < 256; c += 8) {
        float xv[8];
        #pragma unroll
        for (int u = 0; u < 8; ++u)
            xv[u] = xp[(size_t)(c + u) * NPOS];
        #pragma unroll
        for (int u = 0; u < 8; ++u) {
            #pragma unroll
            for (int h = 0; h < NH; ++h)
                acc[h] = fmaf(xv[u], wp[(c + u) * NH + h], acc[h]);
        }
    }
    size_t obase = ((size_t)(cs * BATCH + b) * NH) * NPOS + n;
    #pragma unroll
    for (int h = 0; h < NH; ++h)
        dots[obase + (size_t)h * NPOS] = acc[h];
}

// ---------------------------------------------------------------------------
// K4: softmax over n per (b,h) row; one wave per row; sums the two c-half
// partials; writes attn in place into partial-0 region.
// ---------------------------------------------------------------------------
__global__ __launch_bounds__(256) void k_softmax(float* __restrict__ dots) {
    int row  = blockIdx.x * 4 + (threadIdx.x >> 6);  // 0..511  (b*8+h)
    int lane = threadIdx.x & 63;
    float*       p0 = dots + (size_t)row * NPOS;
    const float* p1 = dots + (size_t)BATCH * NH * NPOS + (size_t)row * NPOS;

    float v[16];
    float m = -INFINITY;
    #pragma unroll
    for (int j = 0; j < 16; ++j) {
        v[j] = p0[lane + 64 * j] + p1[lane + 64 * j];
        m = fmaxf(m, v[j]);
    }
    #pragma unroll
    for (int o = 32; o; o >>= 1) m = fmaxf(m, __shfl_xor(m, o));
    float s = 0.f;
    #pragma unroll
    for (int j = 0; j < 16; ++j) { v[j] = expf(v[j] - m); s += v[j]; }
    #pragma unroll
    for (int o = 32; o; o >>= 1) s += __shfl_xor(s, o);
    float inv = 1.f / s;
    #pragma unroll
    for (int j = 0; j < 16; ++j) p0[lane + 64 * j] = v[j] * inv;
}

// ---------------------------------------------------------------------------
// K5: a[b,h,c] = sum_n attn[b,h,n] * x[b,c,n].  grid (8, B), 256 thr (4 waves).
// attn[b] staged in LDS (32 KiB). Each wave processes 2 c at a time so the
// float4 LDS attn reads are amortized; cross-lane butterfly reduce per (c,h).
// ---------------------------------------------------------------------------
__global__ __launch_bounds__(256) void k_acc(const float* __restrict__ x,
                                             const float* __restrict__ attn,
                                             float* __restrict__ abuf) {
    __shared__ float at[NH][NPOS];
    int b = blockIdx.y, ct = blockIdx.x;

    {
        const float4* src = (const float4*)(attn + (size_t)b * NH * NPOS);
        float4* dst = (float4*)&at[0][0];
        for (int i = threadIdx.x; i < NH * NPOS / 4; i += 256) dst[i] = src[i];
    }
    __syncthreads();

    int w = threadIdx.x >> 6, lane = threadIdx.x & 63;

    for (int cc = 0; cc < 64; cc += 8) {
        int c = ct * 64 + cc + w * 2;  // this wave: c, c+1
        const float* xp0 = x + ((size_t)b * DCH + c) * NPOS;
        const float* xp1 = xp0 + NPOS;
        float acc0[NH], acc1[NH];
        #pragma unroll
        for (int h = 0; h < NH; ++h) { acc0[h] = 0.f; acc1[h] = 0.f; }

        #pragma unroll
        for (int j = 0; j < 4; ++j) {
            int n = j * 256 + lane * 4;
            float4 x0 = *(const float4*)(xp0 + n);
            float4 x1 = *(const float4*)(xp1 + n);
            #pragma unroll
            for (int h = 0; h < NH; ++h) {
                float4 a4 = *(const float4*)&at[h][n];
                acc0[h] += x0.x * a4.x + x0.y * a4.y + x0.z * a4.z + x0.w * a4.w;
                acc1[h] += x1.x * a4.x + x1.y * a4.y + x1.z * a4.z + x1.w * a4.w;
            }
        }
        #pragma unroll
        for (int h = 0; h < NH; ++h) {
            float v0 = acc0[h], v1 = acc1[h];
            #pragma unroll
            for (int o = 32; o; o >>= 1) {
                v0 += __shfl_xor(v0, o);
                v1 += __shfl_xor(v1, o);
            }
            if (lane == 0) {
                abuf[((size_t)b * NH + h) * DCH + c]     = v0;
                abuf[((size_t)b * NH + h) * DCH + c + 1] = v1;
            }
        }
    }
}

// ---------------------------------------------------------------------------
// K6: out[b, h*64+d] = bkv[512+h*64+d] + sum_c a[b,h,c] * Wkv[c, 512+h*64+d]
// ---------------------------------------------------------------------------
__global__ __launch_bounds__(512) void k_out(const float* __restrict__ abuf,
                                             const float* __restrict__ Wkv,
                                             const float* __restrict__ bkv,
                                             float* __restrict__ out) {
    __shared__ float as[NH * DCH];
    int b = blockIdx.x;
    {
        const float4* src = (const float4*)(abuf + (size_t)b * NH * DCH);
        float4* dst = (float4*)as;
        for (int i = threadIdx.x; i < NH * DCH / 4; i += 512) dst[i] = src[i];
    }
    __syncthreads();

    int hd = threadIdx.x;        // 0..511
    int h  = hd >> 6;
    float acc = bkv[DCH + hd];
    const float* wp = Wkv + DCH + hd;
    const float* ap = as + h * DCH;
    #pragma unroll 8
    for (int c = 0; c < DCH; ++c)
        acc = fmaf(ap[c], wp[(size_t)c * (2 * DCH)], acc);
    out[(size_t)b * DCH + hd] = acc;
}

// ---------------------------------------------------------------------------
extern "C" void kernel_launch(void* const* d_in, const int* in_sizes, int n_in,
                              void* d_out, int out_size, void* d_ws, size_t ws_size,
                              hipStream_t stream) {
    const float* x   = (const float*)d_in[0];   // (64, 512, 32, 32)
    const float* q   = (const float*)d_in[1];   // (1, 8, 1, 64)
    const float* Wkv = (const float*)d_in[2];   // (512, 1024)
    const float* bkv = (const float*)d_in[3];   // (1024,)
    float* out = (float*)d_out;                 // (64, 512)

    // workspace layout (floats)
    float* ws   = (float*)d_ws;
    float* wqT  = ws;                                   // 512*8
    float* bias = wqT + DCH * NH;                       // 8*1024
    float* dots = bias + NH * NPOS;                     // 2 * 64*8*1024 (partials; attn in-place in partial 0)
    float* abuf = dots + 2 * (size_t)BATCH * NH * NPOS; // 64*8*512
    // total ~5.05 MiB

    hipLaunchKernelGGL(k_wq,      dim3(2),        dim3(256), 0, stream, q, Wkv, wqT);
    hipLaunchKernelGGL(k_bias,    dim3(4),        dim3(256), 0, stream, q, bkv, bias);
    hipLaunchKernelGGL(k_dots,    dim3(8, BATCH), dim3(256), 0, stream, x, wqT, bias, dots);
    hipLaunchKernelGGL(k_softmax, dim3(128),      dim3(256), 0, stream, dots);
    hipLaunchKernelGGL(k_acc,     dim3(8, BATCH), dim3(256), 0, stream, x, dots, abuf);
    hipLaunchKernelGGL(k_out,     dim3(BATCH),    dim3(512), 0, stream, abuf, Wkv, bkv, out);
}

// Round 2
// 130.177 us; speedup vs baseline: 1.3595x; 1.3595x over previous
//
#include <hip/hip_runtime.h>
#include <math.h>

// Problem constants: B=64, D=512, H=W=32 -> N=1024, NH=8, DH=64
#define BATCH 64
#define DCH   512
#define NPOS  1024
#define NH    8
#define DH    64
#define CSPLIT 4           // c split in k_dots
#define PSTRIDE ((size_t)BATCH * NH * NPOS)   // stride between dots partials

// ---------------------------------------------------------------------------
// K1 (fused prep):
//   blocks 0..1 : wqT[c*8+h] = 0.125 * sum_d q[h,d] * Wkv[c, h*64+d]
//   blocks 2..5 : bias[h*1024+n] = 0.125*( sum_i q[h,2i]*sin(n*dt_i)
//                                        + q[h,2i+1]*cos(n*dt_i) + q[h,:].bkv[h,:] )
// float32 trig (sincosf with proper range reduction; angle <= 1023 rad)
// ---------------------------------------------------------------------------
__global__ __launch_bounds__(256) void k_prep(const float* __restrict__ q,
                                              const float* __restrict__ Wkv,
                                              const float* __restrict__ bkv,
                                              float* __restrict__ wqT,
                                              float* __restrict__ bias) {
    int blk = blockIdx.x;
    if (blk < 2) {
        int c = blk * 256 + threadIdx.x;
        const float* wrow = Wkv + (size_t)c * (2 * DCH);
        #pragma unroll
        for (int h = 0; h < NH; ++h) {
            float s = 0.f;
            #pragma unroll 8
            for (int d = 0; d < DH; ++d)
                s = fmaf(q[h * DH + d], wrow[h * DH + d], s);
            wqT[c * NH + h] = 0.125f * s;
        }
    } else {
        int n = (blk - 2) * 256 + threadIdx.x;
        float pq[NH];
        #pragma unroll
        for (int h = 0; h < NH; ++h) pq[h] = 0.f;
        const float kfac2 = -(float)(M_LN10 * 4.0 / M_LN2) / (float)DH; // -log2(10000)/64
        for (int i = 0; i < DH / 2; ++i) {
            float dt  = exp2f((float)(2 * i) * kfac2);
            float ang = (float)n * dt;
            float s, cth;
            sincosf(ang, &s, &cth);
            #pragma unroll
            for (int h = 0; h < NH; ++h)
                pq[h] = fmaf(q[h * DH + 2 * i], s, fmaf(q[h * DH + 2 * i + 1], cth, pq[h]));
        }
        #pragma unroll
        for (int h = 0; h < NH; ++h) {
            float bq = 0.f;
            for (int d = 0; d < DH; ++d)
                bq = fmaf(q[h * DH + d], bkv[h * DH + d], bq);
            bias[h * NPOS + n] = 0.125f * (pq[h] + bq);
        }
    }
}

// ---------------------------------------------------------------------------
// K2: partial dots. grid (16, B): blockIdx.x = nt*4+cs (nt: 256-n tile,
// cs: 128-c chunk). dots[cs*PSTRIDE + (b*8+h)*1024 + n]
// ---------------------------------------------------------------------------
__global__ __launch_bounds__(256) void k_dots(const float* __restrict__ x,
                                              const float* __restrict__ wqT,
                                              const float* __restrict__ bias,
                                              float* __restrict__ dots) {
    int b  = blockIdx.y;
    int nt = blockIdx.x >> 2;
    int cs = blockIdx.x & 3;
    int n  = nt * 256 + threadIdx.x;
    int c0 = cs * 128;

    float acc[NH];
    #pragma unroll
    for (int h = 0; h < NH; ++h)
        acc[h] = (cs == 0) ? bias[h * NPOS + n] : 0.f;

    const float* xp = x + ((size_t)b * DCH + c0) * NPOS + n;
    const float* wp = wqT + c0 * NH;

    for (int c = 0; c < 128; c += 8) {
        float xv[8];
        #pragma unroll
        for (int u = 0; u < 8; ++u)
            xv[u] = xp[(size_t)(c + u) * NPOS];
        #pragma unroll
        for (int u = 0; u < 8; ++u) {
            #pragma unroll
            for (int h = 0; h < NH; ++h)
                acc[h] = fmaf(xv[u], wp[(c + u) * NH + h], acc[h]);
        }
    }
    size_t obase = (size_t)cs * PSTRIDE + ((size_t)b * NH) * NPOS + n;
    #pragma unroll
    for (int h = 0; h < NH; ++h)
        dots[obase + (size_t)h * NPOS] = acc[h];
}

// ---------------------------------------------------------------------------
// K3 (softmax fused + accumulate): grid (8, B), 256 thr (4 waves).
//   phase 1: each wave softmaxes 2 rows (h = 2w, 2w+1) from the 4 c-partials,
//            writes normalized attn into LDS at[8][1024].
//   phase 2: each wave handles 4 c-streams per iter (16 float4 loads in
//            flight), butterfly-reduce, lane0 stores a[b,h,c].
// ---------------------------------------------------------------------------
__global__ __launch_bounds__(256) void k_acc(const float* __restrict__ x,
                                             const float* __restrict__ dots,
                                             float* __restrict__ abuf) {
    __shared__ float at[NH][NPOS];
    int b = blockIdx.y, ct = blockIdx.x;
    int w = threadIdx.x >> 6, lane = threadIdx.x & 63;

    // --- phase 1: softmax of rows 2w, 2w+1 ---
    #pragma unroll
    for (int r = 0; r < 2; ++r) {
        int h = w * 2 + r;
        const float* p = dots + ((size_t)b * NH + h) * NPOS;
        float v[16];
        float m = -INFINITY;
        #pragma unroll
        for (int j = 0; j < 16; ++j) {
            int n = lane + 64 * j;
            float s = p[n] + p[PSTRIDE + n] + p[2 * PSTRIDE + n] + p[3 * PSTRIDE + n];
            v[j] = s;
            m = fmaxf(m, s);
        }
        #pragma unroll
        for (int o = 32; o; o >>= 1) m = fmaxf(m, __shfl_xor(m, o));
        float sum = 0.f;
        #pragma unroll
        for (int j = 0; j < 16; ++j) { v[j] = expf(v[j] - m); sum += v[j]; }
        #pragma unroll
        for (int o = 32; o; o >>= 1) sum += __shfl_xor(sum, o);
        float inv = 1.f / sum;
        #pragma unroll
        for (int j = 0; j < 16; ++j) at[h][lane + 64 * j] = v[j] * inv;
    }
    __syncthreads();

    // --- phase 2: a[b,h,c] = sum_n at[h][n] * x[b,c,n] ---
    for (int cc = 0; cc < 64; cc += 16) {
        int c = ct * 64 + cc + w * 4;   // this wave: c..c+3
        const float* xp = x + ((size_t)b * DCH + c) * NPOS;
        float acc[4][NH];
        #pragma unroll
        for (int u = 0; u < 4; ++u)
            #pragma unroll
            for (int h = 0; h < NH; ++h) acc[u][h] = 0.f;

        #pragma unroll
        for (int j = 0; j < 4; ++j) {
            int n = j * 256 + lane * 4;
            float4 xv[4];
            #pragma unroll
            for (int u = 0; u < 4; ++u)
                xv[u] = *(const float4*)(xp + (size_t)u * NPOS + n);
            #pragma unroll
            for (int h = 0; h < NH; ++h) {
                float4 a4 = *(const float4*)&at[h][n];
                #pragma unroll
                for (int u = 0; u < 4; ++u)
                    acc[u][h] += xv[u].x * a4.x + xv[u].y * a4.y +
                                 xv[u].z * a4.z + xv[u].w * a4.w;
            }
        }
        #pragma unroll
        for (int u = 0; u < 4; ++u) {
            #pragma unroll
            for (int h = 0; h < NH; ++h) {
                float v0 = acc[u][h];
                #pragma unroll
                for (int o = 32; o; o >>= 1) v0 += __shfl_xor(v0, o);
                if (lane == 0)
                    abuf[((size_t)b * NH + h) * DCH + c + u] = v0;
            }
        }
    }
}

// ---------------------------------------------------------------------------
// K4: out[b, h*64+d] = bkv[512+h*64+d] + sum_c a[b,h,c] * Wkv[c, 512+h*64+d]
// ---------------------------------------------------------------------------
__global__ __launch_bounds__(512) void k_out(const float* __restrict__ abuf,
                                             const float* __restrict__ Wkv,
                                             const float* __restrict__ bkv,
                                             float* __restrict__ out) {
    __shared__ float as[NH * DCH];
    int b = blockIdx.x;
    {
        const float4* src = (const float4*)(abuf + (size_t)b * NH * DCH);
        float4* dst = (float4*)as;
        for (int i = threadIdx.x; i < NH * DCH / 4; i += 512) dst[i] = src[i];
    }
    __syncthreads();

    int hd = threadIdx.x;        // 0..511
    int h  = hd >> 6;
    float acc = bkv[DCH + hd];
    const float* wp = Wkv + DCH + hd;
    const float* ap = as + h * DCH;
    #pragma unroll 8
    for (int c = 0; c < DCH; ++c)
        acc = fmaf(ap[c], wp[(size_t)c * (2 * DCH)], acc);
    out[(size_t)b * DCH + hd] = acc;
}

// ---------------------------------------------------------------------------
extern "C" void kernel_launch(void* const* d_in, const int* in_sizes, int n_in,
                              void* d_out, int out_size, void* d_ws, size_t ws_size,
                              hipStream_t stream) {
    const float* x   = (const float*)d_in[0];   // (64, 512, 32, 32)
    const float* q   = (const float*)d_in[1];   // (1, 8, 1, 64)
    const float* Wkv = (const float*)d_in[2];   // (512, 1024)
    const float* bkv = (const float*)d_in[3];   // (1024,)
    float* out = (float*)d_out;                 // (64, 512)

    // workspace layout (floats)
    float* ws   = (float*)d_ws;
    float* wqT  = ws;                                    // 512*8
    float* bias = wqT + DCH * NH;                        // 8*1024
    float* dots = bias + NH * NPOS;                      // CSPLIT * 64*8*1024
    float* abuf = dots + (size_t)CSPLIT * PSTRIDE;       // 64*8*512
    // total ~10.5 MiB

    hipLaunchKernelGGL(k_prep, dim3(6),         dim3(256), 0, stream, q, Wkv, bkv, wqT, bias);
    hipLaunchKernelGGL(k_dots, dim3(16, BATCH), dim3(256), 0, stream, x, wqT, bias, dots);
    hipLaunchKernelGGL(k_acc,  dim3(8, BATCH),  dim3(256), 0, stream, x, dots, abuf);
    hipLaunchKernelGGL(k_out,  dim3(BATCH),     dim3(512), 0, stream, abuf, Wkv, bkv, out);
}

// Round 3
// 122.601 us; speedup vs baseline: 1.4435x; 1.0618x over previous
//
#include <hip/hip_runtime.h>
#include <math.h>

// Problem constants: B=64, D=512, H=W=32 -> N=1024, NH=8, DH=64
#define BATCH  64
#define DCH    512
#define NPOS   1024
#define NH     8
#define NSPLIT 4
#define NRANGE 256     // NPOS / NSPLIT

// ---------------------------------------------------------------------------
// K1: wqT[c*8+h] = 0.125 * sum_d q[h,d] * Wkv[c, h*64+d]
// grid 16 x 256: thread -> (c = blk*32 + t>>3, h = t&7)
// ---------------------------------------------------------------------------
__global__ __launch_bounds__(256) void k_wq(const float* __restrict__ q,
                                            const float* __restrict__ Wkv,
                                            float* __restrict__ wqT) {
    int t = threadIdx.x;
    int h = t & 7;
    int c = blockIdx.x * 32 + (t >> 3);
    const float* wrow = Wkv + (size_t)c * (2 * DCH) + h * 64;
    const float* qh = q + h * 64;
    float s = 0.f;
    #pragma unroll 16
    for (int d = 0; d < 64; ++d) s = fmaf(qh[d], wrow[d], s);
    wqT[c * NH + h] = 0.125f * s;   // coalesced: index = blk*256 + t
}

// ---------------------------------------------------------------------------
// K2 (flash): one x-pass. grid (NSPLIT, B), 512 threads (8 waves).
//  phase 1: s[h,n] partial dots. threads 0-255: c in [0,256), n=n0+t;
//           threads 256-511: c in [256,512), same n set. 16 loads in flight.
//  phase 2: block softmax over the 256-n range (waves 0-3), m/Z partials.
//  phase 3: lane-per-c accumulation a_j[h,c] = sum_n p[n] x[c,n] — no
//           cross-lane reduce; x re-read hits L2/L3.
// ---------------------------------------------------------------------------
__global__ __launch_bounds__(512) void k_flash(const float* __restrict__ x,
                                               const float* __restrict__ q,
                                               const float* __restrict__ bkv,
                                               const float* __restrict__ wqT,
                                               float* __restrict__ apart,  // [NSPLIT][B][NH*DCH]
                                               float* __restrict__ mz) {   // [NSPLIT][B][2*NH]
    __shared__ float sbuf[NH][NRANGE];   // half-1 dot partials
    __shared__ float pbuf[NH][NRANGE];   // softmax numerators
    __shared__ float red[NH][4];         // cross-wave reduce scratch

    int b  = blockIdx.y, ns = blockIdx.x;
    int t  = threadIdx.x;
    int half = t >> 8;        // c-half
    int tn = t & 255;         // n within range
    int n0 = ns * NRANGE;
    int n  = n0 + tn;

    // --- bias for own n (threads of half 0 only): 0.125*(q.pe[n] + q.bk) ---
    float bias[NH];
    if (half == 0) {
        #pragma unroll
        for (int h = 0; h < NH; ++h) bias[h] = 0.f;
        const float kfac2 = -13.2877123795494f / 64.f;   // -log2(10000)/64
        for (int i = 0; i < 32; ++i) {
            float dt = exp2f((float)(2 * i) * kfac2);
            float ang = (float)n * dt;
            float sn, cs;
            sincosf(ang, &sn, &cs);
            #pragma unroll
            for (int h = 0; h < NH; ++h)
                bias[h] = fmaf(q[h * 64 + 2 * i], sn,
                          fmaf(q[h * 64 + 2 * i + 1], cs, bias[h]));
        }
        #pragma unroll
        for (int h = 0; h < NH; ++h) {
            float bq = 0.f;
            for (int d = 0; d < 64; ++d)
                bq = fmaf(q[h * 64 + d], bkv[h * 64 + d], bq);
            bias[h] = 0.125f * (bias[h] + bq);
        }
    }

    // --- phase 1: partial dots over this thread's 256 c ---
    float acc[NH];
    #pragma unroll
    for (int h = 0; h < NH; ++h) acc[h] = 0.f;
    const float* xp = x + ((size_t)b * DCH + half * 256) * NPOS + n;
    const float* wp = wqT + half * 256 * NH;
    for (int c = 0; c < 256; c += 16) {
        float xv[16];
        #pragma unroll
        for (int u = 0; u < 16; ++u)
            xv[u] = xp[(size_t)(c + u) * NPOS];
        #pragma unroll
        for (int u = 0; u < 16; ++u) {
            #pragma unroll
            for (int h = 0; h < NH; ++h)
                acc[h] = fmaf(xv[u], wp[(c + u) * NH + h], acc[h]);
        }
    }
    if (half == 1) {
        #pragma unroll
        for (int h = 0; h < NH; ++h) sbuf[h][tn] = acc[h];
    }
    __syncthreads();

    // --- phase 2: block softmax (waves 0-3) ---
    float sv[NH], mfin[NH];
    int wv = tn >> 6, lane = tn & 63;
    if (half == 0) {
        #pragma unroll
        for (int h = 0; h < NH; ++h) {
            sv[h] = acc[h] + sbuf[h][tn] + bias[h];
            float mm = sv[h];
            #pragma unroll
            for (int o = 32; o; o >>= 1) mm = fmaxf(mm, __shfl_xor(mm, o));
            if (lane == 0) red[h][wv] = mm;
        }
    }
    __syncthreads();
    if (half == 0) {
        #pragma unroll
        for (int h = 0; h < NH; ++h)
            mfin[h] = fmaxf(fmaxf(red[h][0], red[h][1]),
                            fmaxf(red[h][2], red[h][3]));
    }
    __syncthreads();   // red reuse for Z
    if (half == 0) {
        #pragma unroll
        for (int h = 0; h < NH; ++h) {
            float pvh = expf(sv[h] - mfin[h]);
            pbuf[h][tn] = pvh;
            float zz = pvh;
            #pragma unroll
            for (int o = 32; o; o >>= 1) zz += __shfl_xor(zz, o);
            if (lane == 0) red[h][wv] = zz;
        }
    }
    __syncthreads();
    if (t == 0) {
        float* mzp = mz + ((size_t)ns * BATCH + b) * 2 * NH;
        #pragma unroll
        for (int h = 0; h < NH; ++h) {
            mzp[h]      = mfin[h];
            mzp[NH + h] = red[h][0] + red[h][1] + red[h][2] + red[h][3];
        }
    }

    // --- phase 3: a[h][c] for c = wave*64 + lane; n-range from L2/L3 ---
    int w8 = t >> 6;
    int ln = t & 63;
    int c  = w8 * 64 + ln;
    const float* xr = x + ((size_t)b * DCH + c) * NPOS + n0;
    float a[NH];
    #pragma unroll
    for (int h = 0; h < NH; ++h) a[h] = 0.f;
    #pragma unroll 4
    for (int j = 0; j < NRANGE; j += 4) {
        float4 x4 = *(const float4*)(xr + j);
        #pragma unroll
        for (int h = 0; h < NH; ++h) {
            float4 p4 = *(const float4*)&pbuf[h][j];   // broadcast
            a[h] += x4.x * p4.x + x4.y * p4.y + x4.z * p4.z + x4.w * p4.w;
        }
    }
    float* ap = apart + ((size_t)ns * BATCH + b) * (NH * DCH);
    #pragma unroll
    for (int h = 0; h < NH; ++h)
        ap[h * DCH + c] = a[h];    // coalesced: lanes consecutive c
}

// ---------------------------------------------------------------------------
// K3: combine partials + output GEMV. grid (B), 512 threads.
// out[b, h*64+d] = bkv[512+h*64+d] + sum_c (a[h,c]/Z[h]) * Wkv[c, 512+h*64+d]
// ---------------------------------------------------------------------------
__global__ __launch_bounds__(512) void k_comb(const float* __restrict__ apart,
                                              const float* __restrict__ mz,
                                              const float* __restrict__ Wkv,
                                              const float* __restrict__ bkv,
                                              float* __restrict__ out) {
    __shared__ float as[NH * DCH];
    int b = blockIdx.x, t = threadIdx.x;

    float M[NH], Z[NH], fj[NSPLIT][NH];
    #pragma unroll
    for (int h = 0; h < NH; ++h) { M[h] = -1e30f; Z[h] = 0.f; }
    #pragma unroll
    for (int j = 0; j < NSPLIT; ++j) {
        const float* mzp = mz + ((size_t)j * BATCH + b) * 2 * NH;
        #pragma unroll
        for (int h = 0; h < NH; ++h) M[h] = fmaxf(M[h], mzp[h]);
    }
    #pragma unroll
    for (int j = 0; j < NSPLIT; ++j) {
        const float* mzp = mz + ((size_t)j * BATCH + b) * 2 * NH;
        #pragma unroll
        for (int h = 0; h < NH; ++h) {
            fj[j][h] = expf(mzp[h] - M[h]);
            Z[h] = fmaf(fj[j][h], mzp[NH + h], Z[h]);
        }
    }

    int h = t >> 6;                   // = (t*8) >> 9
    float invZ = 0.f, fsel[NSPLIT];
    #pragma unroll
    for (int hh = 0; hh < NH; ++hh) {
        if (hh == h) {
            invZ = 1.f / Z[hh];
            #pragma unroll
            for (int j = 0; j < NSPLIT; ++j) fsel[j] = fj[j][hh];
        }
    }

    int e0 = t * 8;
    float v[8];
    #pragma unroll
    for (int k = 0; k < 8; ++k) v[k] = 0.f;
    #pragma unroll
    for (int j = 0; j < NSPLIT; ++j) {
        const float* src = apart + ((size_t)j * BATCH + b) * (NH * DCH) + e0;
        float4 lo = *(const float4*)(src);
        float4 hi = *(const float4*)(src + 4);
        v[0] = fmaf(fsel[j], lo.x, v[0]);
        v[1] = fmaf(fsel[j], lo.y, v[1]);
        v[2] = fmaf(fsel[j], lo.z, v[2]);
        v[3] = fmaf(fsel[j], lo.w, v[3]);
        v[4] = fmaf(fsel[j], hi.x, v[4]);
        v[5] = fmaf(fsel[j], hi.y, v[5]);
        v[6] = fmaf(fsel[j], hi.z, v[6]);
        v[7] = fmaf(fsel[j], hi.w, v[7]);
    }
    #pragma unroll
    for (int k = 0; k < 8; ++k) as[e0 + k] = v[k] * invZ;
    __syncthreads();

    float accO = bkv[DCH + t];
    const float* wp  = Wkv + DCH + t;
    const float* apr = as + h * DCH;
    #pragma unroll 8
    for (int c = 0; c < DCH; ++c)
        accO = fmaf(apr[c], wp[(size_t)c * (2 * DCH)], accO);
    out[(size_t)b * DCH + t] = accO;
}

// ---------------------------------------------------------------------------
extern "C" void kernel_launch(void* const* d_in, const int* in_sizes, int n_in,
                              void* d_out, int out_size, void* d_ws, size_t ws_size,
                              hipStream_t stream) {
    const float* x   = (const float*)d_in[0];   // (64, 512, 32, 32)
    const float* q   = (const float*)d_in[1];   // (1, 8, 1, 64)
    const float* Wkv = (const float*)d_in[2];   // (512, 1024)
    const float* bkv = (const float*)d_in[3];   // (1024,)
    float* out = (float*)d_out;                 // (64, 512)

    float* ws    = (float*)d_ws;
    float* wqT   = ws;                                   // 512*8
    float* apart = wqT + DCH * NH;                       // NSPLIT*B*NH*DCH = 1M floats
    float* mz    = apart + (size_t)NSPLIT * BATCH * NH * DCH;  // NSPLIT*B*16
    // total ~4.2 MiB

    hipLaunchKernelGGL(k_wq,    dim3(16),             dim3(256), 0, stream, q, Wkv, wqT);
    hipLaunchKernelGGL(k_flash, dim3(NSPLIT, BATCH),  dim3(512), 0, stream, x, q, bkv, wqT, apart, mz);
    hipLaunchKernelGGL(k_comb,  dim3(BATCH),          dim3(512), 0, stream, apart, mz, Wkv, bkv, out);
}

// Round 4
// 122.172 us; speedup vs baseline: 1.4486x; 1.0035x over previous
//
#include <hip/hip_runtime.h>
#include <math.h>

// Problem constants: B=64, D=512, H=W=32 -> N=1024, NH=8, DH=64
#define BATCH  64
#define DCH    512
#define NPOS   1024
#define NH     8
#define NSPLIT 16
#define NRANGE 64      // NPOS / NSPLIT

// ---------------------------------------------------------------------------
// K1: wqT[c*8+h] = 0.125 * sum_d q[h,d] * Wkv[c, h*64+d]
// ---------------------------------------------------------------------------
__global__ __launch_bounds__(256) void k_wq(const float* __restrict__ q,
                                            const float* __restrict__ Wkv,
                                            float* __restrict__ wqT) {
    int t = threadIdx.x;
    int h = t & 7;
    int c = blockIdx.x * 32 + (t >> 3);
    const float* wrow = Wkv + (size_t)c * (2 * DCH) + h * 64;
    const float* qh = q + h * 64;
    float s = 0.f;
    #pragma unroll 16
    for (int d = 0; d < 64; ++d) s = fmaf(qh[d], wrow[d], s);
    wqT[c * NH + h] = 0.125f * s;
}

// ---------------------------------------------------------------------------
// K2 (flash): grid (NSPLIT=16, B) = 1024 blocks, 512 threads, 4 blocks/CU.
//  phase 1: 8-way c-split dots; thread (oct = t>>6, tn = t&63) covers
//           c in [oct*64, oct*64+64), n = ns*64+tn. LDS reduce.
//  phase 2: wave h owns head h: bias + in-wave softmax over the 64-n range.
//  phase 3: lane-per-c (c = t) partial a over 64 n; pbuf broadcast reads.
// ---------------------------------------------------------------------------
__global__ __launch_bounds__(512, 8) void k_flash(const float* __restrict__ x,
                                                  const float* __restrict__ q,
                                                  const float* __restrict__ bkv,
                                                  const float* __restrict__ wqT,
                                                  float* __restrict__ apart,  // [NSPLIT][B][NH*DCH]
                                                  float* __restrict__ mz) {   // [NSPLIT][B][2*NH]
    __shared__ float sred[8][NH][NRANGE];   // 16 KB
    __shared__ float pbuf[NH][NRANGE];      // 2 KB

    int b  = blockIdx.y, ns = blockIdx.x;
    int t  = threadIdx.x;
    int oct = t >> 6;          // c-octant AND (phase 2) head id
    int tn  = t & 63;
    int n0 = ns * NRANGE;
    int n  = n0 + tn;

    // --- phase 1: partial dots over this thread's 64 c ---
    float acc[NH];
    #pragma unroll
    for (int h = 0; h < NH; ++h) acc[h] = 0.f;
    const float* xp = x + ((size_t)b * DCH + oct * 64) * NPOS + n;
    const float* wp = wqT + oct * 64 * NH;
    for (int c = 0; c < 64; c += 8) {
        float xv[8];
        #pragma unroll
        for (int u = 0; u < 8; ++u)
            xv[u] = xp[(size_t)(c + u) * NPOS];
        #pragma unroll
        for (int u = 0; u < 8; ++u) {
            #pragma unroll
            for (int h = 0; h < NH; ++h)
                acc[h] = fmaf(xv[u], wp[(c + u) * NH + h], acc[h]);
        }
    }
    #pragma unroll
    for (int h = 0; h < NH; ++h) sred[oct][h][tn] = acc[h];
    __syncthreads();

    // --- phase 2: wave h = oct does full softmax for head h over 64 n ---
    {
        int h = oct;
        const float* qh = q + h * 64;
        float bias = 0.f;
        const float kfac2 = -13.2877123795494f / 64.f;   // -log2(10000)/64
        for (int i = 0; i < 32; ++i) {
            float dt = exp2f((float)(2 * i) * kfac2);
            float ang = (float)n * dt;
            float sn, cs;
            sincosf(ang, &sn, &cs);
            bias = fmaf(qh[2 * i], sn, fmaf(qh[2 * i + 1], cs, bias));
        }
        float qbk = 0.f;
        #pragma unroll 8
        for (int d = 0; d < 64; ++d)
            qbk = fmaf(qh[d], bkv[h * 64 + d], qbk);
        float s = 0.125f * (bias + qbk);
        #pragma unroll
        for (int o = 0; o < 8; ++o) s += sred[o][h][tn];

        float m = s;
        #pragma unroll
        for (int o = 32; o; o >>= 1) m = fmaxf(m, __shfl_xor(m, o));
        float p = expf(s - m);
        float z = p;
        #pragma unroll
        for (int o = 32; o; o >>= 1) z += __shfl_xor(z, o);
        pbuf[h][tn] = p;
        if (tn == 0) {
            float* mzp = mz + ((size_t)ns * BATCH + b) * 2 * NH;
            mzp[h]      = m;
            mzp[NH + h] = z;
        }
    }
    __syncthreads();

    // --- phase 3: a[h][c] for c = t over this block's 64 n ---
    const float* xr = x + ((size_t)b * DCH + t) * NPOS + n0;
    float a[NH];
    #pragma unroll
    for (int h = 0; h < NH; ++h) a[h] = 0.f;
    #pragma unroll 4
    for (int j = 0; j < NRANGE; j += 4) {
        float4 x4 = *(const float4*)(xr + j);
        #pragma unroll
        for (int h = 0; h < NH; ++h) {
            float4 p4 = *(const float4*)&pbuf[h][j];   // broadcast
            a[h] += x4.x * p4.x + x4.y * p4.y + x4.z * p4.z + x4.w * p4.w;
        }
    }
    float* ap = apart + ((size_t)ns * BATCH + b) * (NH * DCH);
    #pragma unroll
    for (int h = 0; h < NH; ++h)
        ap[h * DCH + t] = a[h];
}

// ---------------------------------------------------------------------------
// K3: combine 16 partials + output GEMV. grid (B), 512 threads.
// ---------------------------------------------------------------------------
__global__ __launch_bounds__(512) void k_comb(const float* __restrict__ apart,
                                              const float* __restrict__ mz,
                                              const float* __restrict__ Wkv,
                                              const float* __restrict__ bkv,
                                              float* __restrict__ out) {
    __shared__ float as[NH * DCH];
    int b = blockIdx.x, t = threadIdx.x;
    int h = t >> 6;

    float M = -1e30f;
    #pragma unroll
    for (int j = 0; j < NSPLIT; ++j)
        M = fmaxf(M, mz[((size_t)j * BATCH + b) * 2 * NH + h]);
    float Z = 0.f, fj[NSPLIT];
    #pragma unroll
    for (int j = 0; j < NSPLIT; ++j) {
        const float* mzp = mz + ((size_t)j * BATCH + b) * 2 * NH;
        fj[j] = expf(mzp[h] - M);
        Z = fmaf(fj[j], mzp[NH + h], Z);
    }
    float invZ = 1.f / Z;

    int e0 = t * 8;
    float v[8];
    #pragma unroll
    for (int k = 0; k < 8; ++k) v[k] = 0.f;
    #pragma unroll
    for (int j = 0; j < NSPLIT; ++j) {
        const float* src = apart + ((size_t)j * BATCH + b) * (NH * DCH) + e0;
        float4 lo = *(const float4*)(src);
        float4 hi = *(const float4*)(src + 4);
        v[0] = fmaf(fj[j], lo.x, v[0]);
        v[1] = fmaf(fj[j], lo.y, v[1]);
        v[2] = fmaf(fj[j], lo.z, v[2]);
        v[3] = fmaf(fj[j], lo.w, v[3]);
        v[4] = fmaf(fj[j], hi.x, v[4]);
        v[5] = fmaf(fj[j], hi.y, v[5]);
        v[6] = fmaf(fj[j], hi.z, v[6]);
        v[7] = fmaf(fj[j], hi.w, v[7]);
    }
    #pragma unroll
    for (int k = 0; k < 8; ++k) as[e0 + k] = v[k] * invZ;
    __syncthreads();

    float a0 = bkv[DCH + t], a1 = 0.f, a2 = 0.f, a3 = 0.f;
    const float* wp  = Wkv + DCH + t;
    const float* apr = as + h * DCH;
    #pragma unroll 4
    for (int c = 0; c < DCH; c += 4) {
        a0 = fmaf(apr[c],     wp[(size_t)c * (2 * DCH)],       a0);
        a1 = fmaf(apr[c + 1], wp[(size_t)(c + 1) * (2 * DCH)], a1);
        a2 = fmaf(apr[c + 2], wp[(size_t)(c + 2) * (2 * DCH)], a2);
        a3 = fmaf(apr[c + 3], wp[(size_t)(c + 3) * (2 * DCH)], a3);
    }
    out[(size_t)b * DCH + t] = (a0 + a1) + (a2 + a3);
}

// ---------------------------------------------------------------------------
extern "C" void kernel_launch(void* const* d_in, const int* in_sizes, int n_in,
                              void* d_out, int out_size, void* d_ws, size_t ws_size,
                              hipStream_t stream) {
    const float* x   = (const float*)d_in[0];   // (64, 512, 32, 32)
    const float* q   = (const float*)d_in[1];   // (1, 8, 1, 64)
    const float* Wkv = (const float*)d_in[2];   // (512, 1024)
    const float* bkv = (const float*)d_in[3];   // (1024,)
    float* out = (float*)d_out;                 // (64, 512)

    float* ws    = (float*)d_ws;
    float* wqT   = ws;                                         // 512*8
    float* apart = wqT + DCH * NH;                             // 16*64*4096 = 16 MiB
    float* mz    = apart + (size_t)NSPLIT * BATCH * NH * DCH;  // 16*64*16

    hipLaunchKernelGGL(k_wq,    dim3(16),            dim3(256), 0, stream, q, Wkv, wqT);
    hipLaunchKernelGGL(k_flash, dim3(NSPLIT, BATCH), dim3(512), 0, stream, x, q, bkv, wqT, apart, mz);
    hipLaunchKernelGGL(k_comb,  dim3(BATCH),         dim3(512), 0, stream, apart, mz, Wkv, bkv, out);
}

// Round 5
// 110.426 us; speedup vs baseline: 1.6027x; 1.1064x over previous
//
#include <hip/hip_runtime.h>
#include <math.h>

// Problem constants: B=64, D=512, H=W=32 -> N=1024, NH=8, DH=64
#define BATCH  64
#define DCH    512
#define NPOS   1024
#define NH     8
#define NSPLIT 16
#define NRANGE 64      // NPOS / NSPLIT

// ---------------------------------------------------------------------------
// K1 (prep): blocks 0-1: wqT[c*8+h] = 0.125 * sum_d q[h,d]*Wkv[c,h*64+d]
//            blocks 2-5: bias[h*1024+n] = 0.125*(q.pe[n] + q.bkv)  (f32 trig)
// ---------------------------------------------------------------------------
__global__ __launch_bounds__(256) void k_prep(const float* __restrict__ q,
                                              const float* __restrict__ Wkv,
                                              const float* __restrict__ bkv,
                                              float* __restrict__ wqT,
                                              float* __restrict__ bias) {
    int blk = blockIdx.x;
    if (blk < 2) {
        int c = blk * 256 + threadIdx.x;
        const float4* wrow = (const float4*)(Wkv + (size_t)c * (2 * DCH));
        const float4* q4   = (const float4*)q;
        #pragma unroll
        for (int h = 0; h < NH; ++h) {
            float s = 0.f;
            #pragma unroll
            for (int d4 = 0; d4 < 16; ++d4) {
                float4 a = q4[h * 16 + d4];
                float4 w = wrow[h * 16 + d4];
                s = fmaf(a.x, w.x, fmaf(a.y, w.y, fmaf(a.z, w.z, fmaf(a.w, w.w, s))));
            }
            wqT[c * NH + h] = 0.125f * s;
        }
    } else {
        int n = (blk - 2) * 256 + threadIdx.x;
        float pq[NH];
        #pragma unroll
        for (int h = 0; h < NH; ++h) pq[h] = 0.f;
        const float kfac2 = -13.2877123795494f / 64.f;   // -log2(10000)/64
        for (int i = 0; i < 32; ++i) {
            float dt = exp2f((float)(2 * i) * kfac2);
            float ang = (float)n * dt;
            float sn, cs;
            sincosf(ang, &sn, &cs);
            #pragma unroll
            for (int h = 0; h < NH; ++h)
                pq[h] = fmaf(q[h * 64 + 2 * i], sn,
                        fmaf(q[h * 64 + 2 * i + 1], cs, pq[h]));
        }
        #pragma unroll
        for (int h = 0; h < NH; ++h) {
            float bq = 0.f;
            #pragma unroll 8
            for (int d = 0; d < 64; ++d)
                bq = fmaf(q[h * 64 + d], bkv[h * 64 + d], bq);
            bias[h * NPOS + n] = 0.125f * (pq[h] + bq);
        }
    }
}

// ---------------------------------------------------------------------------
// K2 (flash): grid (NSPLIT=16, B) = 1024 blocks, 512 threads, 2 blocks/CU.
// Lane mapping: rg = lane>>4 (row-group), n4 = lane&15 (n-quad).
// Wave w owns c-stripe [w*64, w*64+64); chunk k covers rows c0+4k+rg.
//  phase 1: x4 loads (16 full lines/instr) + LDS-broadcast weights -> dots
//  phase 2: wave h = head h softmax (bias table from global)
//  phase 3: p in regs (8h x 4n), x4 re-read (L3), DPP butterfly over n4
// ---------------------------------------------------------------------------
__global__ __launch_bounds__(512, 4) void k_flash(const float* __restrict__ x,
                                                  const float* __restrict__ wqT,
                                                  const float* __restrict__ bias,
                                                  float* __restrict__ apart,  // [NSPLIT][B][NH][DCH]
                                                  float* __restrict__ mz) {   // [NSPLIT][B][16]
    __shared__ float wqs[DCH * NH];        // 16 KB  [c*8+h]
    __shared__ float sred[8][NH][NRANGE];  // 16 KB
    __shared__ float pbuf[NH][NRANGE];     // 2 KB

    int b = blockIdx.y, ns = blockIdx.x;
    int t = threadIdx.x;
    int w = t >> 6;
    int lane = t & 63;
    int rg = lane >> 4;
    int n4 = lane & 15;
    int n0 = ns * NRANGE;
    int c0 = w * 64;

    // stage wq -> LDS (coalesced float4, 2 per thread)
    {
        const float4* src = (const float4*)wqT;
        float4* dst = (float4*)wqs;
        #pragma unroll
        for (int i = 0; i < 2; ++i) dst[t + 512 * i] = src[t + 512 * i];
    }
    __syncthreads();

    const float* xbase = x + ((size_t)b * DCH + c0 + rg) * NPOS + n0 + n4 * 4;

    // --- phase 1: dots partials ---
    float acc[NH][4];
    #pragma unroll
    for (int h = 0; h < NH; ++h)
        #pragma unroll
        for (int e = 0; e < 4; ++e) acc[h][e] = 0.f;

    #pragma unroll 4
    for (int k = 0; k < 16; ++k) {
        float4 xv = *(const float4*)(xbase + (size_t)(4 * k) * NPOS);
        int c = c0 + 4 * k + rg;
        float wv[8];
        *(float4*)&wv[0] = *(const float4*)&wqs[c * 8];
        *(float4*)&wv[4] = *(const float4*)&wqs[c * 8 + 4];
        #pragma unroll
        for (int h = 0; h < NH; ++h) {
            acc[h][0] = fmaf(xv.x, wv[h], acc[h][0]);
            acc[h][1] = fmaf(xv.y, wv[h], acc[h][1]);
            acc[h][2] = fmaf(xv.z, wv[h], acc[h][2]);
            acc[h][3] = fmaf(xv.w, wv[h], acc[h][3]);
        }
    }
    // reduce across the 4 row-groups (lanes xor 16, 32)
    #pragma unroll
    for (int h = 0; h < NH; ++h)
        #pragma unroll
        for (int e = 0; e < 4; ++e) {
            float v = acc[h][e];
            v += __shfl_xor(v, 16);
            v += __shfl_xor(v, 32);
            acc[h][e] = v;
        }
    if (rg == 0) {
        #pragma unroll
        for (int h = 0; h < NH; ++h)
            *(float4*)&sred[w][h][n4 * 4] =
                make_float4(acc[h][0], acc[h][1], acc[h][2], acc[h][3]);
    }
    __syncthreads();

    // --- phase 2: wave h = w does softmax for head h over 64 n ---
    {
        int h = w;
        int n = lane;
        float s = bias[h * NPOS + n0 + n];
        #pragma unroll
        for (int o = 0; o < 8; ++o) s += sred[o][h][n];
        float m = s;
        #pragma unroll
        for (int o = 32; o; o >>= 1) m = fmaxf(m, __shfl_xor(m, o));
        float p = expf(s - m);
        float z = p;
        #pragma unroll
        for (int o = 32; o; o >>= 1) z += __shfl_xor(z, o);
        pbuf[h][n] = p;
        if (lane == 0) {
            float* mzp = mz + ((size_t)ns * BATCH + b) * 2 * NH;
            mzp[h]      = m;
            mzp[NH + h] = z;
        }
    }
    __syncthreads();

    // --- phase 3: a[h][c], p in registers, x4 re-read (L3-hot) ---
    float p4[NH][4];
    #pragma unroll
    for (int h = 0; h < NH; ++h)
        *(float4*)&p4[h][0] = *(const float4*)&pbuf[h][n4 * 4];

    size_t abase = ((size_t)ns * BATCH + b) * (NH * DCH);
    #pragma unroll 2
    for (int k = 0; k < 16; ++k) {
        float4 xv = *(const float4*)(xbase + (size_t)(4 * k) * NPOS);
        float con[NH];
        #pragma unroll
        for (int h = 0; h < NH; ++h) {
            con[h] = fmaf(xv.x, p4[h][0], fmaf(xv.y, p4[h][1],
                     fmaf(xv.z, p4[h][2], xv.w * p4[h][3])));
        }
        #pragma unroll
        for (int h = 0; h < NH; ++h) {
            #pragma unroll
            for (int o = 1; o < 16; o <<= 1)
                con[h] += __shfl_xor(con[h], o);
        }
        // writer lanes: n4 == h (32 active: 4 rg x 8 h), one store instr
        float val = con[0];
        #pragma unroll
        for (int h = 1; h < NH; ++h) val = (n4 == h) ? con[h] : val;
        if (n4 < NH) {
            int c = c0 + 4 * k + rg;
            apart[abase + (size_t)n4 * DCH + c] = val;
        }
    }
}

// ---------------------------------------------------------------------------
// K3: combine 16 partials + output GEMV. grid (B, 2), 512 threads.
// ---------------------------------------------------------------------------
__global__ __launch_bounds__(512) void k_comb(const float* __restrict__ apart,
                                              const float* __restrict__ mz,
                                              const float* __restrict__ Wkv,
                                              const float* __restrict__ bkv,
                                              float* __restrict__ out) {
    __shared__ float as[NH * DCH];
    __shared__ float red[2][256];
    int b = blockIdx.x, half = blockIdx.y, t = threadIdx.x;
    int h = t >> 6;

    float M = -1e30f;
    #pragma unroll
    for (int j = 0; j < NSPLIT; ++j)
        M = fmaxf(M, mz[((size_t)j * BATCH + b) * 2 * NH + h]);
    float Z = 0.f, fj[NSPLIT];
    #pragma unroll
    for (int j = 0; j < NSPLIT; ++j) {
        const float* mzp = mz + ((size_t)j * BATCH + b) * 2 * NH;
        fj[j] = expf(mzp[h] - M);
        Z = fmaf(fj[j], mzp[NH + h], Z);
    }
    float invZ = 1.f / Z;

    int e0 = t * 8;
    float v[8];
    #pragma unroll
    for (int k = 0; k < 8; ++k) v[k] = 0.f;
    #pragma unroll
    for (int j = 0; j < NSPLIT; ++j) {
        const float* src = apart + ((size_t)j * BATCH + b) * (NH * DCH) + e0;
        float4 lo = *(const float4*)(src);
        float4 hi = *(const float4*)(src + 4);
        v[0] = fmaf(fj[j], lo.x, v[0]);
        v[1] = fmaf(fj[j], lo.y, v[1]);
        v[2] = fmaf(fj[j], lo.z, v[2]);
        v[3] = fmaf(fj[j], lo.w, v[3]);
        v[4] = fmaf(fj[j], hi.x, v[4]);
        v[5] = fmaf(fj[j], hi.y, v[5]);
        v[6] = fmaf(fj[j], hi.z, v[6]);
        v[7] = fmaf(fj[j], hi.w, v[7]);
    }
    #pragma unroll
    for (int k = 0; k < 8; ++k) as[e0 + k] = v[k] * invZ;
    __syncthreads();

    int o  = t & 255;
    int cp = t >> 8;
    int hd = half * 256 + o;
    int ho = hd >> 6;
    float a0 = 0.f, a1 = 0.f, a2 = 0.f, a3 = 0.f;
    const float* wp  = Wkv + DCH + hd;
    const float* apr = as + ho * DCH;
    int cbeg = cp * 256;
    #pragma unroll 4
    for (int c = cbeg; c < cbeg + 256; c += 4) {
        a0 = fmaf(apr[c],     wp[(size_t)c * (2 * DCH)],       a0);
        a1 = fmaf(apr[c + 1], wp[(size_t)(c + 1) * (2 * DCH)], a1);
        a2 = fmaf(apr[c + 2], wp[(size_t)(c + 2) * (2 * DCH)], a2);
        a3 = fmaf(apr[c + 3], wp[(size_t)(c + 3) * (2 * DCH)], a3);
    }
    red[cp][o] = (a0 + a1) + (a2 + a3);
    __syncthreads();
    if (t < 256) {
        int hd2 = half * 256 + t;
        out[(size_t)b * DCH + hd2] = bkv[DCH + hd2] + red[0][t] + red[1][t];
    }
}

// ---------------------------------------------------------------------------
extern "C" void kernel_launch(void* const* d_in, const int* in_sizes, int n_in,
                              void* d_out, int out_size, void* d_ws, size_t ws_size,
                              hipStream_t stream) {
    const float* x   = (const float*)d_in[0];   // (64, 512, 32, 32)
    const float* q   = (const float*)d_in[1];   // (1, 8, 1, 64)
    const float* Wkv = (const float*)d_in[2];   // (512, 1024)
    const float* bkv = (const float*)d_in[3];   // (1024,)
    float* out = (float*)d_out;                 // (64, 512)

    float* ws    = (float*)d_ws;
    float* wqT   = ws;                                         // 512*8
    float* bias  = wqT + DCH * NH;                             // 8*1024
    float* apart = bias + NH * NPOS;                           // 16*64*4096 = 16 MiB
    float* mz    = apart + (size_t)NSPLIT * BATCH * NH * DCH;  // 16*64*16

    hipLaunchKernelGGL(k_prep,  dim3(6),             dim3(256), 0, stream, q, Wkv, bkv, wqT, bias);
    hipLaunchKernelGGL(k_flash, dim3(NSPLIT, BATCH), dim3(512), 0, stream, x, wqT, bias, apart, mz);
    hipLaunchKernelGGL(k_comb,  dim3(BATCH, 2),      dim3(512), 0, stream, apart, mz, Wkv, bkv, out);
}

// Round 6
// 84.482 us; speedup vs baseline: 2.0948x; 1.3071x over previous
//
#include <hip/hip_runtime.h>
#include <math.h>

// Problem constants: B=64, D=512, H=W=32 -> N=1024, NH=8, DH=64
#define BATCH  64
#define DCH    512
#define NPOS   1024
#define NH     8
#define NSPLIT 16
#define NRANGE 64      // NPOS / NSPLIT

// ---------------------------------------------------------------------------
// K1 (prep): blocks 0-1: wqT[c*8+h] = 0.125 * sum_d q[h,d]*Wkv[c,h*64+d]
//            blocks 2-5: bias[h*1024+n] = 0.125*(q.pe[n] + q.bkv)
// ---------------------------------------------------------------------------
__global__ __launch_bounds__(256) void k_prep(const float* __restrict__ q,
                                              const float* __restrict__ Wkv,
                                              const float* __restrict__ bkv,
                                              float* __restrict__ wqT,
                                              float* __restrict__ bias) {
    int blk = blockIdx.x;
    if (blk < 2) {
        int c = blk * 256 + threadIdx.x;
        const float4* wrow = (const float4*)(Wkv + (size_t)c * (2 * DCH));
        const float4* q4   = (const float4*)q;
        #pragma unroll
        for (int h = 0; h < NH; ++h) {
            float s = 0.f;
            #pragma unroll
            for (int d4 = 0; d4 < 16; ++d4) {
                float4 a = q4[h * 16 + d4];
                float4 w = wrow[h * 16 + d4];
                s = fmaf(a.x, w.x, fmaf(a.y, w.y, fmaf(a.z, w.z, fmaf(a.w, w.w, s))));
            }
            wqT[c * NH + h] = 0.125f * s;
        }
    } else {
        int n = (blk - 2) * 256 + threadIdx.x;
        float pq[NH];
        #pragma unroll
        for (int h = 0; h < NH; ++h) pq[h] = 0.f;
        const float kfac2 = -13.2877123795494f / 64.f;   // -log2(10000)/64
        for (int i = 0; i < 32; ++i) {
            float dt = exp2f((float)(2 * i) * kfac2);
            float ang = (float)n * dt;
            float sn, cs;
            sincosf(ang, &sn, &cs);
            #pragma unroll
            for (int h = 0; h < NH; ++h)
                pq[h] = fmaf(q[h * 64 + 2 * i], sn,
                        fmaf(q[h * 64 + 2 * i + 1], cs, pq[h]));
        }
        #pragma unroll
        for (int h = 0; h < NH; ++h) {
            float bq = 0.f;
            #pragma unroll 8
            for (int d = 0; d < 64; ++d)
                bq = fmaf(q[h * 64 + d], bkv[h * 64 + d], bq);
            bias[h * NPOS + n] = 0.125f * (pq[h] + bq);
        }
    }
}

// ---------------------------------------------------------------------------
// K2 (flash): grid (NSPLIT=16, B), 512 threads, 2 blocks/CU.
//  phase 1: lane=(rg=l>>4, n4=l&15); 8 float4 loads in flight; LDS weights.
//  phase 2: wave h = head h in-wave softmax (precomputed bias table).
//  phase 3: lane=(rg3=l>>2, nq=l&3); 16 rows/pass-set, 16 n/thread; p in
//           regs via per-j LDS broadcast; quad_perm-only reduction.
// ---------------------------------------------------------------------------
__global__ __launch_bounds__(512, 4) void k_flash(const float* __restrict__ x,
                                                  const float* __restrict__ wqT,
                                                  const float* __restrict__ bias,
                                                  float* __restrict__ apart,  // [NSPLIT][B][NH][DCH]
                                                  float* __restrict__ mz) {   // [NSPLIT][B][16]
    __shared__ float wqs[DCH * NH];        // 16 KB  [c*8+h]
    __shared__ float sred[8][NH][NRANGE];  // 16 KB
    __shared__ float pbuf[NH][NRANGE];     // 2 KB

    int b = blockIdx.y, ns = blockIdx.x;
    int t = threadIdx.x;
    int w = t >> 6;
    int lane = t & 63;
    int n0 = ns * NRANGE;
    int c0 = w * 64;

    // stage wq -> LDS
    {
        const float4* src = (const float4*)wqT;
        float4* dst = (float4*)wqs;
        #pragma unroll
        for (int i = 0; i < 2; ++i) dst[t + 512 * i] = src[t + 512 * i];
    }
    __syncthreads();

    // ---------------- phase 1: dots partials ----------------
    {
        int rg = lane >> 4;      // 4 row-groups
        int n4 = lane & 15;      // 16 n-quads
        const float* xbase = x + ((size_t)b * DCH + c0 + rg) * NPOS + n0 + n4 * 4;

        float acc[NH][4];
        #pragma unroll
        for (int h = 0; h < NH; ++h)
            #pragma unroll
            for (int e = 0; e < 4; ++e) acc[h][e] = 0.f;

        #pragma unroll
        for (int g = 0; g < 2; ++g) {
            float4 xv[8];
            #pragma unroll
            for (int u = 0; u < 8; ++u)
                xv[u] = *(const float4*)(xbase + (size_t)(4 * (8 * g + u)) * NPOS);
            #pragma unroll
            for (int u = 0; u < 8; ++u) {
                int c = c0 + 4 * (8 * g + u) + rg;
                float wv[8];
                *(float4*)&wv[0] = *(const float4*)&wqs[c * 8];
                *(float4*)&wv[4] = *(const float4*)&wqs[c * 8 + 4];
                #pragma unroll
                for (int h = 0; h < NH; ++h) {
                    acc[h][0] = fmaf(xv[u].x, wv[h], acc[h][0]);
                    acc[h][1] = fmaf(xv[u].y, wv[h], acc[h][1]);
                    acc[h][2] = fmaf(xv[u].z, wv[h], acc[h][2]);
                    acc[h][3] = fmaf(xv[u].w, wv[h], acc[h][3]);
                }
            }
        }
        // reduce across the 4 row-groups (xor 16, 32)
        #pragma unroll
        for (int h = 0; h < NH; ++h)
            #pragma unroll
            for (int e = 0; e < 4; ++e) {
                float v = acc[h][e];
                v += __shfl_xor(v, 16);
                v += __shfl_xor(v, 32);
                acc[h][e] = v;
            }
        if (rg == 0) {
            #pragma unroll
            for (int h = 0; h < NH; ++h)
                *(float4*)&sred[w][h][n4 * 4] =
                    make_float4(acc[h][0], acc[h][1], acc[h][2], acc[h][3]);
        }
    }
    __syncthreads();

    // ---------------- phase 2: softmax (wave w = head w) ----------------
    {
        int h = w;
        int n = lane;
        float s = bias[h * NPOS + n0 + n];
        #pragma unroll
        for (int o = 0; o < 8; ++o) s += sred[o][h][n];
        float m = s;
        #pragma unroll
        for (int o = 32; o; o >>= 1) m = fmaxf(m, __shfl_xor(m, o));
        float p = expf(s - m);
        float z = p;
        #pragma unroll
        for (int o = 32; o; o >>= 1) z += __shfl_xor(z, o);
        pbuf[h][n] = p;
        if (lane == 0) {
            float* mzp = mz + ((size_t)ns * BATCH + b) * 2 * NH;
            mzp[h]      = m;
            mzp[NH + h] = z;
        }
    }
    __syncthreads();

    // ---------------- phase 3: a[h][c] ----------------
    {
        int rg = lane >> 2;      // 16 rows per pass-set
        int nq = lane & 3;       // 4 n-quads of 16 B, 16 n per thread
        const float* xb3 = x + ((size_t)b * DCH + c0 + rg) * NPOS + n0 + nq * 4;

        float con[4][NH];
        #pragma unroll
        for (int p = 0; p < 4; ++p)
            #pragma unroll
            for (int h = 0; h < NH; ++h) con[p][h] = 0.f;

        // double-buffered j loop: 8 loads in flight at the j boundary
        float4 xcur[4], xnxt[4];
        #pragma unroll
        for (int p = 0; p < 4; ++p)
            xcur[p] = *(const float4*)(xb3 + (size_t)(p * 16) * NPOS);

        #pragma unroll
        for (int j = 0; j < 4; ++j) {
            if (j < 3) {
                #pragma unroll
                for (int p = 0; p < 4; ++p)
                    xnxt[p] = *(const float4*)(xb3 + (size_t)(p * 16) * NPOS + (j + 1) * 16);
            }
            float4 pj[NH];
            #pragma unroll
            for (int h = 0; h < NH; ++h)
                pj[h] = *(const float4*)&pbuf[h][j * 16 + nq * 4];
            #pragma unroll
            for (int p = 0; p < 4; ++p) {
                #pragma unroll
                for (int h = 0; h < NH; ++h)
                    con[p][h] = fmaf(xcur[p].x, pj[h].x, fmaf(xcur[p].y, pj[h].y,
                                fmaf(xcur[p].z, pj[h].z, fmaf(xcur[p].w, pj[h].w, con[p][h]))));
            }
            #pragma unroll
            for (int p = 0; p < 4; ++p) xcur[p] = xnxt[p];
        }

        // reduce over nq (quad_perm xor1, xor2 — pure VALU)
        #pragma unroll
        for (int p = 0; p < 4; ++p)
            #pragma unroll
            for (int h = 0; h < NH; ++h) {
                float v = con[p][h];
                v += __shfl_xor(v, 1);
                v += __shfl_xor(v, 2);
                con[p][h] = v;
            }

        size_t abase = ((size_t)ns * BATCH + b) * (NH * DCH);
        #pragma unroll
        for (int p = 0; p < 4; ++p) {
            int c = c0 + p * 16 + rg;
            // lane nq stores heads nq and nq+4 (static cndmask selection)
            float lo = (nq == 0) ? con[p][0] : (nq == 1) ? con[p][1]
                     : (nq == 2) ? con[p][2] : con[p][3];
            float hi = (nq == 0) ? con[p][4] : (nq == 1) ? con[p][5]
                     : (nq == 2) ? con[p][6] : con[p][7];
            apart[abase + (size_t)nq * DCH + c]       = lo;
            apart[abase + (size_t)(nq + 4) * DCH + c] = hi;
        }
    }
}

// ---------------------------------------------------------------------------
// K3: combine 16 partials + output GEMV. grid (B, 2), 512 threads.
// ---------------------------------------------------------------------------
__global__ __launch_bounds__(512) void k_comb(const float* __restrict__ apart,
                                              const float* __restrict__ mz,
                                              const float* __restrict__ Wkv,
                                              const float* __restrict__ bkv,
                                              float* __restrict__ out) {
    __shared__ float as[NH * DCH];
    __shared__ float red[2][256];
    int b = blockIdx.x, half = blockIdx.y, t = threadIdx.x;
    int h = t >> 6;

    float M = -1e30f;
    #pragma unroll
    for (int j = 0; j < NSPLIT; ++j)
        M = fmaxf(M, mz[((size_t)j * BATCH + b) * 2 * NH + h]);
    float Z = 0.f, fj[NSPLIT];
    #pragma unroll
    for (int j = 0; j < NSPLIT; ++j) {
        const float* mzp = mz + ((size_t)j * BATCH + b) * 2 * NH;
        fj[j] = expf(mzp[h] - M);
        Z = fmaf(fj[j], mzp[NH + h], Z);
    }
    float invZ = 1.f / Z;

    int e0 = t * 8;
    float v[8];
    #pragma unroll
    for (int k = 0; k < 8; ++k) v[k] = 0.f;
    #pragma unroll
    for (int j = 0; j < NSPLIT; ++j) {
        const float* src = apart + ((size_t)j * BATCH + b) * (NH * DCH) + e0;
        float4 lo = *(const float4*)(src);
        float4 hi = *(const float4*)(src + 4);
        v[0] = fmaf(fj[j], lo.x, v[0]);
        v[1] = fmaf(fj[j], lo.y, v[1]);
        v[2] = fmaf(fj[j], lo.z, v[2]);
        v[3] = fmaf(fj[j], lo.w, v[3]);
        v[4] = fmaf(fj[j], hi.x, v[4]);
        v[5] = fmaf(fj[j], hi.y, v[5]);
        v[6] = fmaf(fj[j], hi.z, v[6]);
        v[7] = fmaf(fj[j], hi.w, v[7]);
    }
    #pragma unroll
    for (int k = 0; k < 8; ++k) as[e0 + k] = v[k] * invZ;
    __syncthreads();

    int o  = t & 255;
    int cp = t >> 8;
    int hd = half * 256 + o;
    int ho = hd >> 6;
    float a0 = 0.f, a1 = 0.f, a2 = 0.f, a3 = 0.f;
    const float* wp  = Wkv + DCH + hd;
    const float* apr = as + ho * DCH;
    int cbeg = cp * 256;
    #pragma unroll 4
    for (int c = cbeg; c < cbeg + 256; c += 4) {
        a0 = fmaf(apr[c],     wp[(size_t)c * (2 * DCH)],       a0);
        a1 = fmaf(apr[c + 1], wp[(size_t)(c + 1) * (2 * DCH)], a1);
        a2 = fmaf(apr[c + 2], wp[(size_t)(c + 2) * (2 * DCH)], a2);
        a3 = fmaf(apr[c + 3], wp[(size_t)(c + 3) * (2 * DCH)], a3);
    }
    red[cp][o] = (a0 + a1) + (a2 + a3);
    __syncthreads();
    if (t < 256) {
        int hd2 = half * 256 + t;
        out[(size_t)b * DCH + hd2] = bkv[DCH + hd2] + red[0][t] + red[1][t];
    }
}

// ---------------------------------------------------------------------------
extern "C" void kernel_launch(void* const* d_in, const int* in_sizes, int n_in,
                              void* d_out, int out_size, void* d_ws, size_t ws_size,
                              hipStream_t stream) {
    const float* x   = (const float*)d_in[0];   // (64, 512, 32, 32)
    const float* q   = (const float*)d_in[1];   // (1, 8, 1, 64)
    const float* Wkv = (const float*)d_in[2];   // (512, 1024)
    const float* bkv = (const float*)d_in[3];   // (1024,)
    float* out = (float*)d_out;                 // (64, 512)

    float* ws    = (float*)d_ws;
    float* wqT   = ws;                                         // 512*8
    float* bias  = wqT + DCH * NH;                             // 8*1024
    float* apart = bias + NH * NPOS;                           // 16 MiB
    float* mz    = apart + (size_t)NSPLIT * BATCH * NH * DCH;  // 16*64*16

    hipLaunchKernelGGL(k_prep,  dim3(6),             dim3(256), 0, stream, q, Wkv, bkv, wqT, bias);
    hipLaunchKernelGGL(k_flash, dim3(NSPLIT, BATCH), dim3(512), 0, stream, x, wqT, bias, apart, mz);
    hipLaunchKernelGGL(k_comb,  dim3(BATCH, 2),      dim3(512), 0, stream, apart, mz, Wkv, bkv, out);
}